// Round 6
// baseline (432.266 us; speedup 1.0000x reference)
//
#include <hip/hip_runtime.h>
#include <cstdint>

typedef float f32x4 __attribute__((ext_vector_type(4)));
typedef __bf16 bf16x8 __attribute__((ext_vector_type(8)));
typedef __bf16 bf16x4 __attribute__((ext_vector_type(4)));

// Problem constants
// B=2, D=256, L=512, NL=2, DS=16, DC=4
// group a: tokens M=512,  dm=512, di=1024, r=32, NX->64, P=8,  KS=8
// group b: tokens M=1024, dm=256, di=512,  r=16, NX->64, P=16, KS=4

// ---------------- weight f32 -> bf16 conversion (4 big segments) ----------------
__global__ __launch_bounds__(256)
void cvt4(const float* __restrict__ s0, const float* __restrict__ s1,
          const float* __restrict__ s2, const float* __restrict__ s3,
          __bf16* __restrict__ d0, __bf16* __restrict__ d1,
          __bf16* __restrict__ d2, __bf16* __restrict__ d3,
          int n0, int n1, int n2, int n3)
{
    int idx = (blockIdx.x * 256 + threadIdx.x) * 4;
    const float* s; __bf16* d; int off;
    if (idx < n0) { s = s0; d = d0; off = idx; }
    else if (idx < n0 + n1) { s = s1; d = d1; off = idx - n0; }
    else if (idx < n0 + n1 + n2) { s = s2; d = d2; off = idx - n0 - n1; }
    else if (idx < n0 + n1 + n2 + n3) { s = s3; d = d3; off = idx - n0 - n1 - n2; }
    else return;
    f32x4 v = *(const f32x4*)(s + off);
    bf16x4 o;
#pragma unroll
    for (int j = 0; j < 4; ++j) o[j] = (__bf16)v[j];
    *(bf16x4*)(d + off) = o;
}

// ------- padded conversion: xproj (rows pad to 64) and dt_w (cols pad to 32) -------
__device__ __forceinline__ void cvt_pad_one(const float* src, __bf16* dst, int rem,
                                            int rs, int cs, int rd, int cd)
{
    const int c = rem % cd;
    const int rfull = rem / cd;
    const int layer = rfull / rd;
    const int r = rfull % rd;
    float v = (r < rs && c < cs) ? src[((size_t)layer * rs + r) * cs + c] : 0.f;
    dst[rem] = (__bf16)v;
}

__global__ __launch_bounds__(256)
void cvt_pad4(const float* __restrict__ xp_a, const float* __restrict__ xp_b,
              const float* __restrict__ dt_a, const float* __restrict__ dt_b,
              __bf16* __restrict__ o_xp_a, __bf16* __restrict__ o_xp_b,
              __bf16* __restrict__ o_dt_a, __bf16* __restrict__ o_dt_b)
{
    const int n0 = 131072, n1 = 65536, n2 = 65536, n3 = 32768;
    int idx = blockIdx.x * 256 + threadIdx.x;
    if (idx < n0) cvt_pad_one(xp_a, o_xp_a, idx, 64, 1024, 64, 1024);
    else if (idx < n0 + n1) cvt_pad_one(xp_b, o_xp_b, idx - n0, 48, 512, 64, 512);
    else if (idx < n0 + n1 + n2) cvt_pad_one(dt_a, o_dt_a, idx - n0 - n1, 1024, 32, 1024, 32);
    else if (idx < n0 + n1 + n2 + n3) cvt_pad_one(dt_b, o_dt_b, idx - n0 - n1 - n2, 512, 16, 512, 32);
}

// ---------------- MFMA GEMM: C(M,N) = A(M,K) @ W(N,K)^T ----------------
__global__ __launch_bounds__(256)
void gemm_bf16(const float* __restrict__ A, const __bf16* __restrict__ W,
               float* __restrict__ C, int M, int N, int K)
{
    __shared__ __bf16 sA[64 * 64];
    __shared__ __bf16 sW[64 * 64];
    const int tid = threadIdx.x;
    const int bm = blockIdx.y * 64, bn = blockIdx.x * 64;
    const int lane = tid & 63, wv = tid >> 6;
    const int m_off = (wv & 1) * 32, n_off = (wv >> 1) * 32;
    const int fr = lane & 15, fq = lane >> 4;
    f32x4 acc[2][2] = {};

    for (int k0 = 0; k0 < K; k0 += 64) {
#pragma unroll
        for (int i = 0; i < 2; ++i) {
            const int cid = i * 256 + tid;
            const int row = cid >> 3, kc = cid & 7;
            const int slot = kc ^ (row & 7);
            const float* sa = A + (size_t)(bm + row) * K + k0 + kc * 8;
            f32x4 v0 = *(const f32x4*)sa;
            f32x4 v1 = *(const f32x4*)(sa + 4);
            bf16x8 ab;
#pragma unroll
            for (int j = 0; j < 4; ++j) { ab[j] = (__bf16)v0[j]; ab[4 + j] = (__bf16)v1[j]; }
            *(bf16x8*)&sA[row * 64 + slot * 8] = ab;
            *(bf16x8*)&sW[row * 64 + slot * 8] =
                *(const bf16x8*)(W + (size_t)(bn + row) * K + k0 + kc * 8);
        }
        __syncthreads();
#pragma unroll
        for (int ks = 0; ks < 2; ++ks) {
            const int kc = ks * 4 + fq;
            const int r0 = m_off + fr, r1 = m_off + 16 + fr;
            const int c0 = n_off + fr, c1 = n_off + 16 + fr;
            bf16x8 a0 = *(const bf16x8*)&sA[r0 * 64 + (kc ^ (r0 & 7)) * 8];
            bf16x8 a1 = *(const bf16x8*)&sA[r1 * 64 + (kc ^ (r1 & 7)) * 8];
            bf16x8 b0 = *(const bf16x8*)&sW[c0 * 64 + (kc ^ (c0 & 7)) * 8];
            bf16x8 b1 = *(const bf16x8*)&sW[c1 * 64 + (kc ^ (c1 & 7)) * 8];
            acc[0][0] = __builtin_amdgcn_mfma_f32_16x16x32_bf16(a0, b0, acc[0][0], 0, 0, 0);
            acc[0][1] = __builtin_amdgcn_mfma_f32_16x16x32_bf16(a0, b1, acc[0][1], 0, 0, 0);
            acc[1][0] = __builtin_amdgcn_mfma_f32_16x16x32_bf16(a1, b0, acc[1][0], 0, 0, 0);
            acc[1][1] = __builtin_amdgcn_mfma_f32_16x16x32_bf16(a1, b1, acc[1][1], 0, 0, 0);
        }
        __syncthreads();
    }
#pragma unroll
    for (int i = 0; i < 2; ++i)
#pragma unroll
        for (int j = 0; j < 2; ++j)
#pragma unroll
            for (int r = 0; r < 4; ++r)
                C[(size_t)(bm + m_off + i * 16 + fq * 4 + r) * N
                  + bn + n_off + j * 16 + fr] = acc[i][j][r];
}

// ---- same GEMM, transposed store: dst[(b*N + col)*Lb + t] (+ optional resid) ----
__global__ __launch_bounds__(256)
void gemm_bf16_tr(const float* __restrict__ A, const __bf16* __restrict__ W,
                  float* __restrict__ dst, const float* __restrict__ resid,
                  int M, int N, int K, int Lb)
{
    __shared__ __bf16 sA[64 * 64];
    __shared__ __bf16 sW[64 * 64];
    const int tid = threadIdx.x;
    const int bm = blockIdx.y * 64, bn = blockIdx.x * 64;
    const int lane = tid & 63, wv = tid >> 6;
    const int m_off = (wv & 1) * 32, n_off = (wv >> 1) * 32;
    const int fr = lane & 15, fq = lane >> 4;
    f32x4 acc[2][2] = {};

    for (int k0 = 0; k0 < K; k0 += 64) {
#pragma unroll
        for (int i = 0; i < 2; ++i) {
            const int cid = i * 256 + tid;
            const int row = cid >> 3, kc = cid & 7;
            const int slot = kc ^ (row & 7);
            const float* sa = A + (size_t)(bm + row) * K + k0 + kc * 8;
            f32x4 v0 = *(const f32x4*)sa;
            f32x4 v1 = *(const f32x4*)(sa + 4);
            bf16x8 ab;
#pragma unroll
            for (int j = 0; j < 4; ++j) { ab[j] = (__bf16)v0[j]; ab[4 + j] = (__bf16)v1[j]; }
            *(bf16x8*)&sA[row * 64 + slot * 8] = ab;
            *(bf16x8*)&sW[row * 64 + slot * 8] =
                *(const bf16x8*)(W + (size_t)(bn + row) * K + k0 + kc * 8);
        }
        __syncthreads();
#pragma unroll
        for (int ks = 0; ks < 2; ++ks) {
            const int kc = ks * 4 + fq;
            const int r0 = m_off + fr, r1 = m_off + 16 + fr;
            const int c0 = n_off + fr, c1 = n_off + 16 + fr;
            bf16x8 a0 = *(const bf16x8*)&sA[r0 * 64 + (kc ^ (r0 & 7)) * 8];
            bf16x8 a1 = *(const bf16x8*)&sA[r1 * 64 + (kc ^ (r1 & 7)) * 8];
            bf16x8 b0 = *(const bf16x8*)&sW[c0 * 64 + (kc ^ (c0 & 7)) * 8];
            bf16x8 b1 = *(const bf16x8*)&sW[c1 * 64 + (kc ^ (c1 & 7)) * 8];
            acc[0][0] = __builtin_amdgcn_mfma_f32_16x16x32_bf16(a0, b0, acc[0][0], 0, 0, 0);
            acc[0][1] = __builtin_amdgcn_mfma_f32_16x16x32_bf16(a0, b1, acc[0][1], 0, 0, 0);
            acc[1][0] = __builtin_amdgcn_mfma_f32_16x16x32_bf16(a1, b0, acc[1][0], 0, 0, 0);
            acc[1][1] = __builtin_amdgcn_mfma_f32_16x16x32_bf16(a1, b1, acc[1][1], 0, 0, 0);
        }
        __syncthreads();
    }
#pragma unroll
    for (int i = 0; i < 2; ++i)
#pragma unroll
        for (int j = 0; j < 2; ++j) {
            const int gn = bn + n_off + j * 16 + fr;
#pragma unroll
            for (int r = 0; r < 4; ++r) {
                const int gm = bm + m_off + i * 16 + fq * 4 + r;
                const int b = gm / Lb, t = gm - b * Lb;
                const size_t o = ((size_t)(b * N + gn)) * Lb + t;
                dst[o] = acc[i][j][r] + (resid ? resid[o] : 0.f);
            }
        }
}

// ------------- x_proj split-K partial GEMM: pbuf[ks][M][64] -------------
// grid (KS, M/64). A bf16 (M,K), W bf16 (64,K). KC = K/KS, multiple of 64.
__global__ __launch_bounds__(256)
void gemm_xp_part(const __bf16* __restrict__ A, const __bf16* __restrict__ W,
                  float* __restrict__ pbuf, int M, int K, int KC)
{
    __shared__ __bf16 sA[64 * 64];
    __shared__ __bf16 sW[64 * 64];
    const int tid = threadIdx.x;
    const int bm = blockIdx.y * 64;
    const int kb = blockIdx.x * KC;
    const int lane = tid & 63, wv = tid >> 6;
    const int m_off = (wv & 1) * 32, n_off = (wv >> 1) * 32;
    const int fr = lane & 15, fq = lane >> 4;
    f32x4 acc[2][2] = {};

    for (int k0 = kb; k0 < kb + KC; k0 += 64) {
#pragma unroll
        for (int i = 0; i < 2; ++i) {
            const int cid = i * 256 + tid;
            const int row = cid >> 3, kc = cid & 7;
            const int slot = kc ^ (row & 7);
            *(bf16x8*)&sA[row * 64 + slot * 8] =
                *(const bf16x8*)(A + (size_t)(bm + row) * K + k0 + kc * 8);
            *(bf16x8*)&sW[row * 64 + slot * 8] =
                *(const bf16x8*)(W + (size_t)row * K + k0 + kc * 8);
        }
        __syncthreads();
#pragma unroll
        for (int ks = 0; ks < 2; ++ks) {
            const int kc = ks * 4 + fq;
            const int r0 = m_off + fr, r1 = m_off + 16 + fr;
            const int c0 = n_off + fr, c1 = n_off + 16 + fr;
            bf16x8 a0 = *(const bf16x8*)&sA[r0 * 64 + (kc ^ (r0 & 7)) * 8];
            bf16x8 a1 = *(const bf16x8*)&sA[r1 * 64 + (kc ^ (r1 & 7)) * 8];
            bf16x8 b0 = *(const bf16x8*)&sW[c0 * 64 + (kc ^ (c0 & 7)) * 8];
            bf16x8 b1 = *(const bf16x8*)&sW[c1 * 64 + (kc ^ (c1 & 7)) * 8];
            acc[0][0] = __builtin_amdgcn_mfma_f32_16x16x32_bf16(a0, b0, acc[0][0], 0, 0, 0);
            acc[0][1] = __builtin_amdgcn_mfma_f32_16x16x32_bf16(a0, b1, acc[0][1], 0, 0, 0);
            acc[1][0] = __builtin_amdgcn_mfma_f32_16x16x32_bf16(a1, b0, acc[1][0], 0, 0, 0);
            acc[1][1] = __builtin_amdgcn_mfma_f32_16x16x32_bf16(a1, b1, acc[1][1], 0, 0, 0);
        }
        __syncthreads();
    }
    float* out = pbuf + (size_t)blockIdx.x * M * 64;
#pragma unroll
    for (int i = 0; i < 2; ++i)
#pragma unroll
        for (int j = 0; j < 2; ++j)
#pragma unroll
            for (int r = 0; r < 4; ++r)
                out[(size_t)(bm + m_off + i * 16 + fq * 4 + r) * 64
                    + n_off + j * 16 + fr] = acc[i][j][r];
}

// ------- dt GEMM (K=32) from partials + bias + softplus; also reduces x_dbl -------
// grid (N/64, M/64), N = DI. pbuf: KS x M x 64 partials.
__global__ __launch_bounds__(256)
void gemm_dt_red(const float* __restrict__ pbuf, const __bf16* __restrict__ W,
                 const float* __restrict__ bias, float* __restrict__ dt_out,
                 float* __restrict__ xdbl, int M, int N, int KS)
{
    const int tid = threadIdx.x, lane = tid & 63, wv = tid >> 6;
    const int bm = blockIdx.y * 64 + (wv & 1) * 32;
    const int bn = blockIdx.x * 64 + (wv >> 1) * 32;
    const int fr = lane & 15, fq = lane >> 4;

    // A fragments: sum partials for rows (bm+fr), (bm+16+fr), cols fq*8..fq*8+7 (<32)
    bf16x8 afr[2];
#pragma unroll
    for (int i = 0; i < 2; ++i) {
        const int row = bm + i * 16 + fr;
        f32x4 s0 = {0.f, 0.f, 0.f, 0.f}, s1 = {0.f, 0.f, 0.f, 0.f};
        for (int ks = 0; ks < KS; ++ks) {
            const float* p = pbuf + (size_t)ks * M * 64 + (size_t)row * 64 + fq * 8;
            s0 += *(const f32x4*)p;
            s1 += *(const f32x4*)(p + 4);
        }
        bf16x8 a;
#pragma unroll
        for (int j = 0; j < 4; ++j) { a[j] = (__bf16)s0[j]; a[4 + j] = (__bf16)s1[j]; }
        afr[i] = a;
    }
    bf16x8 b0 = *(const bf16x8*)&W[(size_t)(bn + fr) * 32 + fq * 8];
    bf16x8 b1 = *(const bf16x8*)&W[(size_t)(bn + 16 + fr) * 32 + fq * 8];
    f32x4 acc[2][2] = {};
    acc[0][0] = __builtin_amdgcn_mfma_f32_16x16x32_bf16(afr[0], b0, acc[0][0], 0, 0, 0);
    acc[0][1] = __builtin_amdgcn_mfma_f32_16x16x32_bf16(afr[0], b1, acc[0][1], 0, 0, 0);
    acc[1][0] = __builtin_amdgcn_mfma_f32_16x16x32_bf16(afr[1], b0, acc[1][0], 0, 0, 0);
    acc[1][1] = __builtin_amdgcn_mfma_f32_16x16x32_bf16(afr[1], b1, acc[1][1], 0, 0, 0);
#pragma unroll
    for (int i = 0; i < 2; ++i)
#pragma unroll
        for (int j = 0; j < 2; ++j) {
            const int col = bn + j * 16 + fr;
            const float bv = bias[col];
#pragma unroll
            for (int r = 0; r < 4; ++r) {
                const float v = acc[i][j][r] + bv;
                dt_out[(size_t)(bm + i * 16 + fq * 4 + r) * N + col] =
                    fmaxf(v, 0.f) + log1pf(__expf(-fabsf(v)));
            }
        }

    // reduce x_dbl for this 64-row stripe (one block column does it)
    if (blockIdx.x == 0) {
        const int row0 = blockIdx.y * 64;
#pragma unroll
        for (int e = 0; e < 16; ++e) {
            const int idx = e * 256 + tid;
            const int row = idx >> 6, col = idx & 63;
            float s = 0.f;
            for (int ks = 0; ks < KS; ++ks)
                s += pbuf[(size_t)ks * M * 64 + (size_t)(row0 + row) * 64 + col];
            xdbl[(size_t)(row0 + row) * 64 + col] = s;
        }
    }
}

// ---------------- causal depthwise conv (DC=4) + SiLU (f32 + bf16 out) ----------------
__global__ __launch_bounds__(256)
void conv_silu(const float* __restrict__ xz, const float* __restrict__ conv_w,
               const float* __restrict__ conv_b, float* __restrict__ xi_out,
               __bf16* __restrict__ xi_bf, int Bb, int Lb, int DI)
{
    const int idx = blockIdx.x * 256 + threadIdx.x;
    const int total = Bb * Lb * DI;
    if (idx >= total) return;
    const int d = idx % DI;
    const int t = (idx / DI) % Lb;
    const int b = idx / (DI * Lb);
    const float* w = conv_w + (size_t)d * 4;
    float acc = conv_b[d];
    const size_t row2 = (size_t)(b * Lb) * (2 * DI);
#pragma unroll
    for (int j = 0; j < 4; ++j) {
        const int tt = t - 3 + j;
        if (tt >= 0) acc += w[j] * xz[row2 + (size_t)tt * (2 * DI) + d];
    }
    const float v = acc / (1.f + __expf(-acc));
    xi_out[idx] = v;
    xi_bf[idx] = (__bf16)v;
}

// ---------------- chunked parallel selective scan ----------------
// x_dbl stride 64. B at col R+s, C at col R+16+s.
__global__ __launch_bounds__(256)
void scan_p1(const float* __restrict__ dt, const float* __restrict__ xi,
             const float* __restrict__ xdbl, const float* __restrict__ A_log,
             float* __restrict__ wsA, float* __restrict__ wsB,
             int Bb, int Lb, int DI, int R, int P)
{
    const int tid = threadIdx.x;
    const int s = tid & 15, dl = tid >> 4;
    const int nDB = DI / 16;
    const int cpb = P * nDB;
    const int b = blockIdx.x / cpb;
    const int rem = blockIdx.x % cpb;
    const int c = rem / nDB;
    const int d = (rem % nDB) * 16 + dl;
    const int TC = Lb / P;
    const float A = -__expf(A_log[(size_t)d * 16 + s]);
    float h = 0.f, sdt = 0.f;
    const size_t rowbase = (size_t)b * Lb + (size_t)c * TC;
#pragma unroll 4
    for (int t = 0; t < TC; ++t) {
        const size_t m = rowbase + t;
        const float dtv = dt[m * DI + d];
        const float xv  = xi[m * DI + d];
        const float Bv  = xdbl[m * 64 + R + s];
        const float dA = __expf(dtv * A);
        h = fmaf(dA, h, dtv * Bv * xv);
        sdt += dtv;
    }
    const size_t o = ((size_t)(b * P + c) * DI + d) * 16 + s;
    wsA[o] = __expf(sdt * A);
    wsB[o] = h;
}

// p2 folded into p3: each chunk rebuilds its h0 from wsA/wsB of prior chunks.
__global__ __launch_bounds__(256)
void scan_p23(const float* __restrict__ dt, const float* __restrict__ xi,
              const float* __restrict__ xdbl, const float* __restrict__ xz,
              const float* __restrict__ A_log, const float* __restrict__ Dp,
              const float* __restrict__ wsA, const float* __restrict__ wsB,
              float* __restrict__ y, int Bb, int Lb, int DI, int R, int P)
{
    const int tid = threadIdx.x;
    const int s = tid & 15, dl = tid >> 4;
    const int nDB = DI / 16;
    const int cpb = P * nDB;
    const int b = blockIdx.x / cpb;
    const int rem = blockIdx.x % cpb;
    const int c = rem / nDB;
    const int d = (rem % nDB) * 16 + dl;
    const int TC = Lb / P;
    const float A = -__expf(A_log[(size_t)d * 16 + s]);
    const float Dv = Dp[d];

    float h = 0.f;
    for (int cc = 0; cc < c; ++cc) {
        const size_t oc = ((size_t)(b * P + cc) * DI + d) * 16 + s;
        h = fmaf(wsA[oc], h, wsB[oc]);
    }

    const size_t rowbase = (size_t)b * Lb + (size_t)c * TC;
#pragma unroll 2
    for (int t = 0; t < TC; ++t) {
        const size_t m = rowbase + t;
        const float dtv = dt[m * DI + d];
        const float xv  = xi[m * DI + d];
        const float Bv  = xdbl[m * 64 + R + s];
        const float Cv  = xdbl[m * 64 + R + 16 + s];
        const float zv  = xz[m * (size_t)(2 * DI) + DI + d];
        const float dA = __expf(dtv * A);
        h = fmaf(dA, h, dtv * Bv * xv);
        float p = h * Cv;
        p += __shfl_xor(p, 1, 16);
        p += __shfl_xor(p, 2, 16);
        p += __shfl_xor(p, 4, 16);
        p += __shfl_xor(p, 8, 16);
        if (s == 0) {
            const float sig = __fdividef(zv, 1.f + __expf(-zv));
            y[m * DI + d] = (p + Dv * xv) * sig;
        }
    }
}

extern "C" void kernel_launch(void* const* d_in, const int* in_sizes, int n_in,
                              void* d_out, int out_size, void* d_ws, size_t ws_size,
                              hipStream_t stream)
{
    const float* x       = (const float*)d_in[0];
    const float* a_in_w  = (const float*)d_in[1];
    const float* a_convw = (const float*)d_in[2];
    const float* a_convb = (const float*)d_in[3];
    const float* a_xproj = (const float*)d_in[4];
    const float* a_dtw   = (const float*)d_in[5];
    const float* a_dtb   = (const float*)d_in[6];
    const float* a_Alog  = (const float*)d_in[7];
    const float* a_Dp    = (const float*)d_in[8];
    const float* a_outw  = (const float*)d_in[9];
    const float* b_in_w  = (const float*)d_in[10];
    const float* b_convw = (const float*)d_in[11];
    const float* b_convb = (const float*)d_in[12];
    const float* b_xproj = (const float*)d_in[13];
    const float* b_dtw   = (const float*)d_in[14];
    const float* b_dtb   = (const float*)d_in[15];
    const float* b_Alog  = (const float*)d_in[16];
    const float* b_Dp    = (const float*)d_in[17];
    const float* b_outw  = (const float*)d_in[18];

    float* ws = (float*)d_ws;
    float* buf_x   = ws;                 // 262144
    float* buf_xz  = buf_x  + 262144;    // 1048576
    float* buf_xi  = buf_xz + 1048576;   // 524288
    float* buf_dbl = buf_xi + 524288;    // 65536 (M x 64)
    float* buf_dt  = buf_dbl + 65536;    // 524288
    float* buf_y   = buf_dt + 524288;    // 524288
    float* buf_x2  = buf_y  + 524288;    // 262144
    float* buf_wsA = buf_x2 + 262144;    // 262144
    float* buf_wsB = buf_wsA + 262144;   // 262144
    float* buf_pk  = buf_wsB + 262144;   // 262144 (KS x M x 64 partials)
    __bf16* wb      = (__bf16*)(buf_pk + 262144);
    __bf16* wb_a_in  = wb;                        // 2097152
    __bf16* wb_a_out = wb_a_in + 2097152;         // 1048576
    __bf16* wb_b_in  = wb_a_out + 1048576;        // 524288
    __bf16* wb_b_out = wb_b_in + 524288;          // 262144
    __bf16* wb_xp_a  = wb_b_out + 262144;         // 131072 (2,64,1024)
    __bf16* wb_xp_b  = wb_xp_a + 131072;          // 65536  (2,64,512) padded
    __bf16* wb_dt_a  = wb_xp_b + 65536;           // 65536  (2,1024,32)
    __bf16* wb_dt_b  = wb_dt_a + 65536;           // 32768  (2,512,32) padded
    __bf16* buf_xi_bf = wb_dt_b + 32768;          // 524288

    // weight conversions (every launch; deterministic)
    {
        const int n0 = 2097152, n1 = 1048576, n2 = 524288, n3 = 262144;
        const int nt = (n0 + n1 + n2 + n3) / 4;
        cvt4<<<(nt + 255) / 256, 256, 0, stream>>>(
            a_in_w, a_outw, b_in_w, b_outw,
            wb_a_in, wb_a_out, wb_b_in, wb_b_out, n0, n1, n2, n3);
        cvt_pad4<<<(131072 + 65536 + 65536 + 32768) / 256, 256, 0, stream>>>(
            a_xproj, b_xproj, a_dtw, b_dtw, wb_xp_a, wb_xp_b, wb_dt_a, wb_dt_b);
    }

    // -------- group a: Bb=2, Lb=256, dm=512, di=1024, R=32, P=8, KS=8 --------
    for (int k = 0; k < 2; ++k) {
        const int Bb = 2, Lb = 256, DM = 512, DI = 1024, R = 32, P = 8, KS = 8;
        const int M = Bb * Lb;
        const float* src = (k == 0) ? x : buf_x;
        gemm_bf16<<<dim3(2 * DI / 64, M / 64), 256, 0, stream>>>(
            src, wb_a_in + (size_t)k * 2 * DI * DM, buf_xz, M, 2 * DI, DM);
        conv_silu<<<(M * DI + 255) / 256, 256, 0, stream>>>(
            buf_xz, a_convw + (size_t)k * DI * 4, a_convb + (size_t)k * DI,
            buf_xi, buf_xi_bf, Bb, Lb, DI);
        gemm_xp_part<<<dim3(KS, M / 64), 256, 0, stream>>>(
            buf_xi_bf, wb_xp_a + (size_t)k * 64 * DI, buf_pk, M, DI, DI / KS);
        gemm_dt_red<<<dim3(DI / 64, M / 64), 256, 0, stream>>>(
            buf_pk, wb_dt_a + (size_t)k * DI * 32, a_dtb + (size_t)k * DI,
            buf_dt, buf_dbl, M, DI, KS);
        scan_p1<<<Bb * P * DI / 16, 256, 0, stream>>>(
            buf_dt, buf_xi, buf_dbl, a_Alog + (size_t)k * DI * 16,
            buf_wsA, buf_wsB, Bb, Lb, DI, R, P);
        scan_p23<<<Bb * P * DI / 16, 256, 0, stream>>>(
            buf_dt, buf_xi, buf_dbl, buf_xz, a_Alog + (size_t)k * DI * 16,
            a_Dp + (size_t)k * DI, buf_wsA, buf_wsB, buf_y, Bb, Lb, DI, R, P);
        if (k == 0)
            gemm_bf16<<<dim3(DM / 64, M / 64), 256, 0, stream>>>(
                buf_y, wb_a_out + (size_t)k * DM * DI, buf_x, M, DM, DI);
        else
            gemm_bf16_tr<<<dim3(DM / 64, M / 64), 256, 0, stream>>>(
                buf_y, wb_a_out + (size_t)k * DM * DI, buf_x2, nullptr, M, DM, DI, Lb);
    }

    // -------- group b: Bb=2, Lb=512, dm=256, di=512, R=16, P=16, KS=4 --------
    for (int k = 0; k < 2; ++k) {
        const int Bb = 2, Lb = 512, DM = 256, DI = 512, R = 16, P = 16, KS = 4;
        const int M = Bb * Lb;
        const float* src = (k == 0) ? buf_x2 : buf_x;
        gemm_bf16<<<dim3(2 * DI / 64, M / 64), 256, 0, stream>>>(
            src, wb_b_in + (size_t)k * 2 * DI * DM, buf_xz, M, 2 * DI, DM);
        conv_silu<<<(M * DI + 255) / 256, 256, 0, stream>>>(
            buf_xz, b_convw + (size_t)k * DI * 4, b_convb + (size_t)k * DI,
            buf_xi, buf_xi_bf, Bb, Lb, DI);
        gemm_xp_part<<<dim3(KS, M / 64), 256, 0, stream>>>(
            buf_xi_bf, wb_xp_b + (size_t)k * 64 * DI, buf_pk, M, DI, DI / KS);
        gemm_dt_red<<<dim3(DI / 64, M / 64), 256, 0, stream>>>(
            buf_pk, wb_dt_b + (size_t)k * DI * 32, b_dtb + (size_t)k * DI,
            buf_dt, buf_dbl, M, DI, KS);
        scan_p1<<<Bb * P * DI / 16, 256, 0, stream>>>(
            buf_dt, buf_xi, buf_dbl, b_Alog + (size_t)k * DI * 16,
            buf_wsA, buf_wsB, Bb, Lb, DI, R, P);
        scan_p23<<<Bb * P * DI / 16, 256, 0, stream>>>(
            buf_dt, buf_xi, buf_dbl, buf_xz, b_Alog + (size_t)k * DI * 16,
            b_Dp + (size_t)k * DI, buf_wsA, buf_wsB, buf_y, Bb, Lb, DI, R, P);
        if (k == 0)
            gemm_bf16<<<dim3(DM / 64, M / 64), 256, 0, stream>>>(
                buf_y, wb_b_out + (size_t)k * DM * DI, buf_x, M, DM, DI);
        else
            gemm_bf16_tr<<<dim3(DM / 64, M / 64), 256, 0, stream>>>(
                buf_y, wb_b_out + (size_t)k * DM * DI, (float*)d_out, x, M, DM, DI, Lb);
    }
}

// Round 7
// 339.553 us; speedup vs baseline: 1.2730x; 1.2730x over previous
//
#include <hip/hip_runtime.h>
#include <cstdint>

typedef float f32x4 __attribute__((ext_vector_type(4)));
typedef __bf16 bf16x8 __attribute__((ext_vector_type(8)));
typedef __bf16 bf16x4 __attribute__((ext_vector_type(4)));

// Problem constants
// B=2, D=256, L=512, NL=2, DS=16, DC=4
// group a: tokens M=512,  dm=512, di=1024, r=32, NX->64, P=8,  KS=8
// group b: tokens M=1024, dm=256, di=512,  r=16, NX->64, P=16, KS=4

// ---------------- weight f32 -> bf16 conversion (4 big segments) ----------------
__global__ __launch_bounds__(256)
void cvt4(const float* __restrict__ s0, const float* __restrict__ s1,
          const float* __restrict__ s2, const float* __restrict__ s3,
          __bf16* __restrict__ d0, __bf16* __restrict__ d1,
          __bf16* __restrict__ d2, __bf16* __restrict__ d3,
          int n0, int n1, int n2, int n3)
{
    int idx = (blockIdx.x * 256 + threadIdx.x) * 4;
    const float* s; __bf16* d; int off;
    if (idx < n0) { s = s0; d = d0; off = idx; }
    else if (idx < n0 + n1) { s = s1; d = d1; off = idx - n0; }
    else if (idx < n0 + n1 + n2) { s = s2; d = d2; off = idx - n0 - n1; }
    else if (idx < n0 + n1 + n2 + n3) { s = s3; d = d3; off = idx - n0 - n1 - n2; }
    else return;
    f32x4 v = *(const f32x4*)(s + off);
    bf16x4 o;
#pragma unroll
    for (int j = 0; j < 4; ++j) o[j] = (__bf16)v[j];
    *(bf16x4*)(d + off) = o;
}

// ------- padded conversion: xproj (rows pad to 64) and dt_w (cols pad to 32) -------
__device__ __forceinline__ void cvt_pad_one(const float* src, __bf16* dst, int rem,
                                            int rs, int cs, int rd, int cd)
{
    const int c = rem % cd;
    const int rfull = rem / cd;
    const int layer = rfull / rd;
    const int r = rfull % rd;
    float v = (r < rs && c < cs) ? src[((size_t)layer * rs + r) * cs + c] : 0.f;
    dst[rem] = (__bf16)v;
}

__global__ __launch_bounds__(256)
void cvt_pad4(const float* __restrict__ xp_a, const float* __restrict__ xp_b,
              const float* __restrict__ dt_a, const float* __restrict__ dt_b,
              __bf16* __restrict__ o_xp_a, __bf16* __restrict__ o_xp_b,
              __bf16* __restrict__ o_dt_a, __bf16* __restrict__ o_dt_b)
{
    const int n0 = 131072, n1 = 65536, n2 = 65536, n3 = 32768;
    int idx = blockIdx.x * 256 + threadIdx.x;
    if (idx < n0) cvt_pad_one(xp_a, o_xp_a, idx, 64, 1024, 64, 1024);
    else if (idx < n0 + n1) cvt_pad_one(xp_b, o_xp_b, idx - n0, 48, 512, 64, 512);
    else if (idx < n0 + n1 + n2) cvt_pad_one(dt_a, o_dt_a, idx - n0 - n1, 1024, 32, 1024, 32);
    else if (idx < n0 + n1 + n2 + n3) cvt_pad_one(dt_b, o_dt_b, idx - n0 - n1 - n2, 512, 16, 512, 32);
}

// ---------------- MFMA GEMM: C(M,N) = A(M,K) @ W(N,K)^T ----------------
__global__ __launch_bounds__(256)
void gemm_bf16(const float* __restrict__ A, const __bf16* __restrict__ W,
               float* __restrict__ C, int M, int N, int K)
{
    __shared__ __bf16 sA[64 * 64];
    __shared__ __bf16 sW[64 * 64];
    const int tid = threadIdx.x;
    const int bm = blockIdx.y * 64, bn = blockIdx.x * 64;
    const int lane = tid & 63, wv = tid >> 6;
    const int m_off = (wv & 1) * 32, n_off = (wv >> 1) * 32;
    const int fr = lane & 15, fq = lane >> 4;
    f32x4 acc[2][2] = {};

    for (int k0 = 0; k0 < K; k0 += 64) {
#pragma unroll
        for (int i = 0; i < 2; ++i) {
            const int cid = i * 256 + tid;
            const int row = cid >> 3, kc = cid & 7;
            const int slot = kc ^ (row & 7);
            const float* sa = A + (size_t)(bm + row) * K + k0 + kc * 8;
            f32x4 v0 = *(const f32x4*)sa;
            f32x4 v1 = *(const f32x4*)(sa + 4);
            bf16x8 ab;
#pragma unroll
            for (int j = 0; j < 4; ++j) { ab[j] = (__bf16)v0[j]; ab[4 + j] = (__bf16)v1[j]; }
            *(bf16x8*)&sA[row * 64 + slot * 8] = ab;
            *(bf16x8*)&sW[row * 64 + slot * 8] =
                *(const bf16x8*)(W + (size_t)(bn + row) * K + k0 + kc * 8);
        }
        __syncthreads();
#pragma unroll
        for (int ks = 0; ks < 2; ++ks) {
            const int kc = ks * 4 + fq;
            const int r0 = m_off + fr, r1 = m_off + 16 + fr;
            const int c0 = n_off + fr, c1 = n_off + 16 + fr;
            bf16x8 a0 = *(const bf16x8*)&sA[r0 * 64 + (kc ^ (r0 & 7)) * 8];
            bf16x8 a1 = *(const bf16x8*)&sA[r1 * 64 + (kc ^ (r1 & 7)) * 8];
            bf16x8 b0 = *(const bf16x8*)&sW[c0 * 64 + (kc ^ (c0 & 7)) * 8];
            bf16x8 b1 = *(const bf16x8*)&sW[c1 * 64 + (kc ^ (c1 & 7)) * 8];
            acc[0][0] = __builtin_amdgcn_mfma_f32_16x16x32_bf16(a0, b0, acc[0][0], 0, 0, 0);
            acc[0][1] = __builtin_amdgcn_mfma_f32_16x16x32_bf16(a0, b1, acc[0][1], 0, 0, 0);
            acc[1][0] = __builtin_amdgcn_mfma_f32_16x16x32_bf16(a1, b0, acc[1][0], 0, 0, 0);
            acc[1][1] = __builtin_amdgcn_mfma_f32_16x16x32_bf16(a1, b1, acc[1][1], 0, 0, 0);
        }
        __syncthreads();
    }
#pragma unroll
    for (int i = 0; i < 2; ++i)
#pragma unroll
        for (int j = 0; j < 2; ++j)
#pragma unroll
            for (int r = 0; r < 4; ++r)
                C[(size_t)(bm + m_off + i * 16 + fq * 4 + r) * N
                  + bn + n_off + j * 16 + fr] = acc[i][j][r];
}

// ---- same GEMM, transposed store: dst[(b*N + col)*Lb + t] (+ optional resid) ----
__global__ __launch_bounds__(256)
void gemm_bf16_tr(const float* __restrict__ A, const __bf16* __restrict__ W,
                  float* __restrict__ dst, const float* __restrict__ resid,
                  int M, int N, int K, int Lb)
{
    __shared__ __bf16 sA[64 * 64];
    __shared__ __bf16 sW[64 * 64];
    const int tid = threadIdx.x;
    const int bm = blockIdx.y * 64, bn = blockIdx.x * 64;
    const int lane = tid & 63, wv = tid >> 6;
    const int m_off = (wv & 1) * 32, n_off = (wv >> 1) * 32;
    const int fr = lane & 15, fq = lane >> 4;
    f32x4 acc[2][2] = {};

    for (int k0 = 0; k0 < K; k0 += 64) {
#pragma unroll
        for (int i = 0; i < 2; ++i) {
            const int cid = i * 256 + tid;
            const int row = cid >> 3, kc = cid & 7;
            const int slot = kc ^ (row & 7);
            const float* sa = A + (size_t)(bm + row) * K + k0 + kc * 8;
            f32x4 v0 = *(const f32x4*)sa;
            f32x4 v1 = *(const f32x4*)(sa + 4);
            bf16x8 ab;
#pragma unroll
            for (int j = 0; j < 4; ++j) { ab[j] = (__bf16)v0[j]; ab[4 + j] = (__bf16)v1[j]; }
            *(bf16x8*)&sA[row * 64 + slot * 8] = ab;
            *(bf16x8*)&sW[row * 64 + slot * 8] =
                *(const bf16x8*)(W + (size_t)(bn + row) * K + k0 + kc * 8);
        }
        __syncthreads();
#pragma unroll
        for (int ks = 0; ks < 2; ++ks) {
            const int kc = ks * 4 + fq;
            const int r0 = m_off + fr, r1 = m_off + 16 + fr;
            const int c0 = n_off + fr, c1 = n_off + 16 + fr;
            bf16x8 a0 = *(const bf16x8*)&sA[r0 * 64 + (kc ^ (r0 & 7)) * 8];
            bf16x8 a1 = *(const bf16x8*)&sA[r1 * 64 + (kc ^ (r1 & 7)) * 8];
            bf16x8 b0 = *(const bf16x8*)&sW[c0 * 64 + (kc ^ (c0 & 7)) * 8];
            bf16x8 b1 = *(const bf16x8*)&sW[c1 * 64 + (kc ^ (c1 & 7)) * 8];
            acc[0][0] = __builtin_amdgcn_mfma_f32_16x16x32_bf16(a0, b0, acc[0][0], 0, 0, 0);
            acc[0][1] = __builtin_amdgcn_mfma_f32_16x16x32_bf16(a0, b1, acc[0][1], 0, 0, 0);
            acc[1][0] = __builtin_amdgcn_mfma_f32_16x16x32_bf16(a1, b0, acc[1][0], 0, 0, 0);
            acc[1][1] = __builtin_amdgcn_mfma_f32_16x16x32_bf16(a1, b1, acc[1][1], 0, 0, 0);
        }
        __syncthreads();
    }
#pragma unroll
    for (int i = 0; i < 2; ++i)
#pragma unroll
        for (int j = 0; j < 2; ++j) {
            const int gn = bn + n_off + j * 16 + fr;
#pragma unroll
            for (int r = 0; r < 4; ++r) {
                const int gm = bm + m_off + i * 16 + fq * 4 + r;
                const int b = gm / Lb, t = gm - b * Lb;
                const size_t o = ((size_t)(b * N + gn)) * Lb + t;
                dst[o] = acc[i][j][r] + (resid ? resid[o] : 0.f);
            }
        }
}

// ------------- x_proj split-K partial GEMM: pbuf[ks][M][64] -------------
// grid (KS, M/64). A bf16 (M,K), W bf16 (64,K). KC = K/KS, multiple of 64.
__global__ __launch_bounds__(256)
void gemm_xp_part(const __bf16* __restrict__ A, const __bf16* __restrict__ W,
                  float* __restrict__ pbuf, int M, int K, int KC)
{
    __shared__ __bf16 sA[64 * 64];
    __shared__ __bf16 sW[64 * 64];
    const int tid = threadIdx.x;
    const int bm = blockIdx.y * 64;
    const int kb = blockIdx.x * KC;
    const int lane = tid & 63, wv = tid >> 6;
    const int m_off = (wv & 1) * 32, n_off = (wv >> 1) * 32;
    const int fr = lane & 15, fq = lane >> 4;
    f32x4 acc[2][2] = {};

    for (int k0 = kb; k0 < kb + KC; k0 += 64) {
#pragma unroll
        for (int i = 0; i < 2; ++i) {
            const int cid = i * 256 + tid;
            const int row = cid >> 3, kc = cid & 7;
            const int slot = kc ^ (row & 7);
            *(bf16x8*)&sA[row * 64 + slot * 8] =
                *(const bf16x8*)(A + (size_t)(bm + row) * K + k0 + kc * 8);
            *(bf16x8*)&sW[row * 64 + slot * 8] =
                *(const bf16x8*)(W + (size_t)row * K + k0 + kc * 8);
        }
        __syncthreads();
#pragma unroll
        for (int ks = 0; ks < 2; ++ks) {
            const int kc = ks * 4 + fq;
            const int r0 = m_off + fr, r1 = m_off + 16 + fr;
            const int c0 = n_off + fr, c1 = n_off + 16 + fr;
            bf16x8 a0 = *(const bf16x8*)&sA[r0 * 64 + (kc ^ (r0 & 7)) * 8];
            bf16x8 a1 = *(const bf16x8*)&sA[r1 * 64 + (kc ^ (r1 & 7)) * 8];
            bf16x8 b0 = *(const bf16x8*)&sW[c0 * 64 + (kc ^ (c0 & 7)) * 8];
            bf16x8 b1 = *(const bf16x8*)&sW[c1 * 64 + (kc ^ (c1 & 7)) * 8];
            acc[0][0] = __builtin_amdgcn_mfma_f32_16x16x32_bf16(a0, b0, acc[0][0], 0, 0, 0);
            acc[0][1] = __builtin_amdgcn_mfma_f32_16x16x32_bf16(a0, b1, acc[0][1], 0, 0, 0);
            acc[1][0] = __builtin_amdgcn_mfma_f32_16x16x32_bf16(a1, b0, acc[1][0], 0, 0, 0);
            acc[1][1] = __builtin_amdgcn_mfma_f32_16x16x32_bf16(a1, b1, acc[1][1], 0, 0, 0);
        }
        __syncthreads();
    }
    float* out = pbuf + (size_t)blockIdx.x * M * 64;
#pragma unroll
    for (int i = 0; i < 2; ++i)
#pragma unroll
        for (int j = 0; j < 2; ++j)
#pragma unroll
            for (int r = 0; r < 4; ++r)
                out[(size_t)(bm + m_off + i * 16 + fq * 4 + r) * 64
                    + n_off + j * 16 + fr] = acc[i][j][r];
}

// ------- reduce KS partials -> x_dbl f32 + bf16 (read pbuf exactly once) -------
__global__ __launch_bounds__(256)
void xp_reduce(const float* __restrict__ pbuf, float* __restrict__ xdbl,
               __bf16* __restrict__ xdbl_bf, int total, int KS)
{
    const int idx = (blockIdx.x * 256 + threadIdx.x) * 4;
    if (idx >= total) return;
    f32x4 s = {0.f, 0.f, 0.f, 0.f};
    for (int ks = 0; ks < KS; ++ks)
        s += *(const f32x4*)(pbuf + (size_t)ks * total + idx);
    *(f32x4*)(xdbl + idx) = s;
    bf16x4 o;
#pragma unroll
    for (int j = 0; j < 4; ++j) o[j] = (__bf16)s[j];
    *(bf16x4*)(xdbl_bf + idx) = o;
}

// ------------- dt GEMM (K=32, no LDS) + bias + softplus -------------
// out(M,N) = softplus(A(M,64)[:, :32] @ W(N,32)^T + bias). grid (N/64, M/64).
__global__ __launch_bounds__(256)
void gemm_dt(const __bf16* __restrict__ A, const __bf16* __restrict__ W,
             const float* __restrict__ bias, float* __restrict__ out, int M, int N)
{
    const int tid = threadIdx.x, lane = tid & 63, wv = tid >> 6;
    const int bm = blockIdx.y * 64 + (wv & 1) * 32;
    const int bn = blockIdx.x * 64 + (wv >> 1) * 32;
    const int fr = lane & 15, fq = lane >> 4;
    bf16x8 a0 = *(const bf16x8*)&A[(size_t)(bm + fr) * 64 + fq * 8];
    bf16x8 a1 = *(const bf16x8*)&A[(size_t)(bm + 16 + fr) * 64 + fq * 8];
    bf16x8 b0 = *(const bf16x8*)&W[(size_t)(bn + fr) * 32 + fq * 8];
    bf16x8 b1 = *(const bf16x8*)&W[(size_t)(bn + 16 + fr) * 32 + fq * 8];
    f32x4 acc[2][2] = {};
    acc[0][0] = __builtin_amdgcn_mfma_f32_16x16x32_bf16(a0, b0, acc[0][0], 0, 0, 0);
    acc[0][1] = __builtin_amdgcn_mfma_f32_16x16x32_bf16(a0, b1, acc[0][1], 0, 0, 0);
    acc[1][0] = __builtin_amdgcn_mfma_f32_16x16x32_bf16(a1, b0, acc[1][0], 0, 0, 0);
    acc[1][1] = __builtin_amdgcn_mfma_f32_16x16x32_bf16(a1, b1, acc[1][1], 0, 0, 0);
#pragma unroll
    for (int i = 0; i < 2; ++i)
#pragma unroll
        for (int j = 0; j < 2; ++j) {
            const int col = bn + j * 16 + fr;
            const float bv = bias[col];
#pragma unroll
            for (int r = 0; r < 4; ++r) {
                const float v = acc[i][j][r] + bv;
                out[(size_t)(bm + i * 16 + fq * 4 + r) * N + col] =
                    fmaxf(v, 0.f) + log1pf(__expf(-fabsf(v)));
            }
        }
}

// ---------------- causal depthwise conv (DC=4) + SiLU (f32 + bf16 out) ----------------
__global__ __launch_bounds__(256)
void conv_silu(const float* __restrict__ xz, const float* __restrict__ conv_w,
               const float* __restrict__ conv_b, float* __restrict__ xi_out,
               __bf16* __restrict__ xi_bf, int Bb, int Lb, int DI)
{
    const int idx = blockIdx.x * 256 + threadIdx.x;
    const int total = Bb * Lb * DI;
    if (idx >= total) return;
    const int d = idx % DI;
    const int t = (idx / DI) % Lb;
    const int b = idx / (DI * Lb);
    const float* w = conv_w + (size_t)d * 4;
    float acc = conv_b[d];
    const size_t row2 = (size_t)(b * Lb) * (2 * DI);
#pragma unroll
    for (int j = 0; j < 4; ++j) {
        const int tt = t - 3 + j;
        if (tt >= 0) acc += w[j] * xz[row2 + (size_t)tt * (2 * DI) + d];
    }
    const float v = acc / (1.f + __expf(-acc));
    xi_out[idx] = v;
    xi_bf[idx] = (__bf16)v;
}

// ---------------- chunked parallel selective scan ----------------
__global__ __launch_bounds__(256)
void scan_p1(const float* __restrict__ dt, const float* __restrict__ xi,
             const float* __restrict__ xdbl, const float* __restrict__ A_log,
             float* __restrict__ wsA, float* __restrict__ wsB,
             int Bb, int Lb, int DI, int R, int P)
{
    const int tid = threadIdx.x;
    const int s = tid & 15, dl = tid >> 4;
    const int nDB = DI / 16;
    const int cpb = P * nDB;
    const int b = blockIdx.x / cpb;
    const int rem = blockIdx.x % cpb;
    const int c = rem / nDB;
    const int d = (rem % nDB) * 16 + dl;
    const int TC = Lb / P;
    const float A = -__expf(A_log[(size_t)d * 16 + s]);
    float h = 0.f, sdt = 0.f;
    const size_t rowbase = (size_t)b * Lb + (size_t)c * TC;
#pragma unroll 4
    for (int t = 0; t < TC; ++t) {
        const size_t m = rowbase + t;
        const float dtv = dt[m * DI + d];
        const float xv  = xi[m * DI + d];
        const float Bv  = xdbl[m * 64 + R + s];
        const float dA = __expf(dtv * A);
        h = fmaf(dA, h, dtv * Bv * xv);
        sdt += dtv;
    }
    const size_t o = ((size_t)(b * P + c) * DI + d) * 16 + s;
    wsA[o] = __expf(sdt * A);
    wsB[o] = h;
}

// p2 folded into p3: each chunk rebuilds its h0 from wsA/wsB of prior chunks.
__global__ __launch_bounds__(256)
void scan_p23(const float* __restrict__ dt, const float* __restrict__ xi,
              const float* __restrict__ xdbl, const float* __restrict__ xz,
              const float* __restrict__ A_log, const float* __restrict__ Dp,
              const float* __restrict__ wsA, const float* __restrict__ wsB,
              float* __restrict__ y, int Bb, int Lb, int DI, int R, int P)
{
    const int tid = threadIdx.x;
    const int s = tid & 15, dl = tid >> 4;
    const int nDB = DI / 16;
    const int cpb = P * nDB;
    const int b = blockIdx.x / cpb;
    const int rem = blockIdx.x % cpb;
    const int c = rem / nDB;
    const int d = (rem % nDB) * 16 + dl;
    const int TC = Lb / P;
    const float A = -__expf(A_log[(size_t)d * 16 + s]);
    const float Dv = Dp[d];

    float h = 0.f;
    for (int cc = 0; cc < c; ++cc) {
        const size_t oc = ((size_t)(b * P + cc) * DI + d) * 16 + s;
        h = fmaf(wsA[oc], h, wsB[oc]);
    }

    const size_t rowbase = (size_t)b * Lb + (size_t)c * TC;
#pragma unroll 2
    for (int t = 0; t < TC; ++t) {
        const size_t m = rowbase + t;
        const float dtv = dt[m * DI + d];
        const float xv  = xi[m * DI + d];
        const float Bv  = xdbl[m * 64 + R + s];
        const float Cv  = xdbl[m * 64 + R + 16 + s];
        const float zv  = xz[m * (size_t)(2 * DI) + DI + d];
        const float dA = __expf(dtv * A);
        h = fmaf(dA, h, dtv * Bv * xv);
        float p = h * Cv;
        p += __shfl_xor(p, 1, 16);
        p += __shfl_xor(p, 2, 16);
        p += __shfl_xor(p, 4, 16);
        p += __shfl_xor(p, 8, 16);
        if (s == 0) {
            const float sig = __fdividef(zv, 1.f + __expf(-zv));
            y[m * DI + d] = (p + Dv * xv) * sig;
        }
    }
}

extern "C" void kernel_launch(void* const* d_in, const int* in_sizes, int n_in,
                              void* d_out, int out_size, void* d_ws, size_t ws_size,
                              hipStream_t stream)
{
    const float* x       = (const float*)d_in[0];
    const float* a_in_w  = (const float*)d_in[1];
    const float* a_convw = (const float*)d_in[2];
    const float* a_convb = (const float*)d_in[3];
    const float* a_xproj = (const float*)d_in[4];
    const float* a_dtw   = (const float*)d_in[5];
    const float* a_dtb   = (const float*)d_in[6];
    const float* a_Alog  = (const float*)d_in[7];
    const float* a_Dp    = (const float*)d_in[8];
    const float* a_outw  = (const float*)d_in[9];
    const float* b_in_w  = (const float*)d_in[10];
    const float* b_convw = (const float*)d_in[11];
    const float* b_convb = (const float*)d_in[12];
    const float* b_xproj = (const float*)d_in[13];
    const float* b_dtw   = (const float*)d_in[14];
    const float* b_dtb   = (const float*)d_in[15];
    const float* b_Alog  = (const float*)d_in[16];
    const float* b_Dp    = (const float*)d_in[17];
    const float* b_outw  = (const float*)d_in[18];

    float* ws = (float*)d_ws;
    float* buf_x   = ws;                 // 262144
    float* buf_xz  = buf_x  + 262144;    // 1048576
    float* buf_xi  = buf_xz + 1048576;   // 524288
    float* buf_dbl = buf_xi + 524288;    // 65536 (M x 64)
    float* buf_dt  = buf_dbl + 65536;    // 524288
    float* buf_y   = buf_dt + 524288;    // 524288
    float* buf_x2  = buf_y  + 524288;    // 262144
    float* buf_wsA = buf_x2 + 262144;    // 262144
    float* buf_wsB = buf_wsA + 262144;   // 262144
    float* buf_pk  = buf_wsB + 262144;   // 262144 (KS x M x 64 partials)
    __bf16* wb      = (__bf16*)(buf_pk + 262144);
    __bf16* wb_a_in  = wb;                        // 2097152
    __bf16* wb_a_out = wb_a_in + 2097152;         // 1048576
    __bf16* wb_b_in  = wb_a_out + 1048576;        // 524288
    __bf16* wb_b_out = wb_b_in + 524288;          // 262144
    __bf16* wb_xp_a  = wb_b_out + 262144;         // 131072 (2,64,1024)
    __bf16* wb_xp_b  = wb_xp_a + 131072;          // 65536  (2,64,512) padded
    __bf16* wb_dt_a  = wb_xp_b + 65536;           // 65536  (2,1024,32)
    __bf16* wb_dt_b  = wb_dt_a + 65536;           // 32768  (2,512,32) padded
    __bf16* buf_xi_bf  = wb_dt_b + 32768;         // 524288
    __bf16* buf_dbl_bf = buf_xi_bf + 524288;      // 65536

    // weight conversions (every launch; deterministic)
    {
        const int n0 = 2097152, n1 = 1048576, n2 = 524288, n3 = 262144;
        const int nt = (n0 + n1 + n2 + n3) / 4;
        cvt4<<<(nt + 255) / 256, 256, 0, stream>>>(
            a_in_w, a_outw, b_in_w, b_outw,
            wb_a_in, wb_a_out, wb_b_in, wb_b_out, n0, n1, n2, n3);
        cvt_pad4<<<(131072 + 65536 + 65536 + 32768) / 256, 256, 0, stream>>>(
            a_xproj, b_xproj, a_dtw, b_dtw, wb_xp_a, wb_xp_b, wb_dt_a, wb_dt_b);
    }

    // -------- group a: Bb=2, Lb=256, dm=512, di=1024, R=32, P=8, KS=8 --------
    for (int k = 0; k < 2; ++k) {
        const int Bb = 2, Lb = 256, DM = 512, DI = 1024, R = 32, P = 8, KS = 8;
        const int M = Bb * Lb;
        const float* src = (k == 0) ? x : buf_x;
        gemm_bf16<<<dim3(2 * DI / 64, M / 64), 256, 0, stream>>>(
            src, wb_a_in + (size_t)k * 2 * DI * DM, buf_xz, M, 2 * DI, DM);
        conv_silu<<<(M * DI + 255) / 256, 256, 0, stream>>>(
            buf_xz, a_convw + (size_t)k * DI * 4, a_convb + (size_t)k * DI,
            buf_xi, buf_xi_bf, Bb, Lb, DI);
        gemm_xp_part<<<dim3(KS, M / 64), 256, 0, stream>>>(
            buf_xi_bf, wb_xp_a + (size_t)k * 64 * DI, buf_pk, M, DI, DI / KS);
        xp_reduce<<<(M * 64 / 4 + 255) / 256, 256, 0, stream>>>(
            buf_pk, buf_dbl, buf_dbl_bf, M * 64, KS);
        gemm_dt<<<dim3(DI / 64, M / 64), 256, 0, stream>>>(
            buf_dbl_bf, wb_dt_a + (size_t)k * DI * 32, a_dtb + (size_t)k * DI,
            buf_dt, M, DI);
        scan_p1<<<Bb * P * DI / 16, 256, 0, stream>>>(
            buf_dt, buf_xi, buf_dbl, a_Alog + (size_t)k * DI * 16,
            buf_wsA, buf_wsB, Bb, Lb, DI, R, P);
        scan_p23<<<Bb * P * DI / 16, 256, 0, stream>>>(
            buf_dt, buf_xi, buf_dbl, buf_xz, a_Alog + (size_t)k * DI * 16,
            a_Dp + (size_t)k * DI, buf_wsA, buf_wsB, buf_y, Bb, Lb, DI, R, P);
        if (k == 0)
            gemm_bf16<<<dim3(DM / 64, M / 64), 256, 0, stream>>>(
                buf_y, wb_a_out + (size_t)k * DM * DI, buf_x, M, DM, DI);
        else
            gemm_bf16_tr<<<dim3(DM / 64, M / 64), 256, 0, stream>>>(
                buf_y, wb_a_out + (size_t)k * DM * DI, buf_x2, nullptr, M, DM, DI, Lb);
    }

    // -------- group b: Bb=2, Lb=512, dm=256, di=512, R=16, P=16, KS=4 --------
    for (int k = 0; k < 2; ++k) {
        const int Bb = 2, Lb = 512, DM = 256, DI = 512, R = 16, P = 16, KS = 4;
        const int M = Bb * Lb;
        const float* src = (k == 0) ? buf_x2 : buf_x;
        gemm_bf16<<<dim3(2 * DI / 64, M / 64), 256, 0, stream>>>(
            src, wb_b_in + (size_t)k * 2 * DI * DM, buf_xz, M, 2 * DI, DM);
        conv_silu<<<(M * DI + 255) / 256, 256, 0, stream>>>(
            buf_xz, b_convw + (size_t)k * DI * 4, b_convb + (size_t)k * DI,
            buf_xi, buf_xi_bf, Bb, Lb, DI);
        gemm_xp_part<<<dim3(KS, M / 64), 256, 0, stream>>>(
            buf_xi_bf, wb_xp_b + (size_t)k * 64 * DI, buf_pk, M, DI, DI / KS);
        xp_reduce<<<(M * 64 / 4 + 255) / 256, 256, 0, stream>>>(
            buf_pk, buf_dbl, buf_dbl_bf, M * 64, KS);
        gemm_dt<<<dim3(DI / 64, M / 64), 256, 0, stream>>>(
            buf_dbl_bf, wb_dt_b + (size_t)k * DI * 32, b_dtb + (size_t)k * DI,
            buf_dt, M, DI);
        scan_p1<<<Bb * P * DI / 16, 256, 0, stream>>>(
            buf_dt, buf_xi, buf_dbl, b_Alog + (size_t)k * DI * 16,
            buf_wsA, buf_wsB, Bb, Lb, DI, R, P);
        scan_p23<<<Bb * P * DI / 16, 256, 0, stream>>>(
            buf_dt, buf_xi, buf_dbl, buf_xz, b_Alog + (size_t)k * DI * 16,
            b_Dp + (size_t)k * DI, buf_wsA, buf_wsB, buf_y, Bb, Lb, DI, R, P);
        if (k == 0)
            gemm_bf16<<<dim3(DM / 64, M / 64), 256, 0, stream>>>(
                buf_y, wb_b_out + (size_t)k * DM * DI, buf_x, M, DM, DI);
        else
            gemm_bf16_tr<<<dim3(DM / 64, M / 64), 256, 0, stream>>>(
                buf_y, wb_b_out + (size_t)k * DM * DI, (float*)d_out, x, M, DM, DI, Lb);
    }
}